// Round 1
// baseline (424.320 us; speedup 1.0000x reference)
//
#include <hip/hip_runtime.h>

#define CN 256
#define HN 64
#define WN 64
#define NNW 32
#define HW (HN*WN)            // 4096 queries
#define NREF (NNW*HW)         // 131072 refs
#define KD 256                // feature dim

#define BM 128
#define BN 128
#define BK 64
#define NT_PER 32             // n-tiles swept per block

using bf16x8 = __attribute__((ext_vector_type(8))) short;
using f32x4  = __attribute__((ext_vector_type(4))) float;

__device__ inline unsigned short f2bf(float x) {
  // round-to-nearest-even fp32 -> bf16 (inputs finite)
  unsigned int u = __float_as_uint(x);
  unsigned int r = (u + 0x7fffu + ((u >> 16) & 1u)) >> 16;
  return (unsigned short)r;
}

__device__ inline void atomicMaxFloat(float* addr, float val) {
  if (val >= 0.f) atomicMax(reinterpret_cast<int*>(addr), __float_as_int(val));
  else            atomicMin(reinterpret_cast<unsigned int*>(addr), __float_as_uint(val));
}

__device__ inline void gload_lds16(const void* g, void* l) {
  __builtin_amdgcn_global_load_lds(
      (const __attribute__((address_space(1))) void*)g,
      (__attribute__((address_space(3))) void*)l, 16, 0, 0);
}

// ---- normalize refs: (N,C,H,W) fp32 -> R[n*4096+h*64+w][c] bf16 ----
__global__ void norm_refs_kernel(const float* __restrict__ refs,
                                 unsigned short* __restrict__ R) {
  int nh = blockIdx.x;            // 0..2047  (n*64+h)
  int n = nh >> 6, h = nh & 63;
  int w = threadIdx.x;            // 0..63
  const float* base = refs + ((size_t)n * CN) * HW + h * WN + w;
  float ss = 0.f;
#pragma unroll 4
  for (int c = 0; c < CN; ++c) { float v = base[(size_t)c * HW]; ss += v * v; }
  float sc = 1.f / fmaxf(sqrtf(ss), 1e-12f);
  unsigned short* o = R + ((size_t)nh * WN + w) * KD;
#pragma unroll 4
  for (int c = 0; c < CN; ++c) o[c] = f2bf(base[(size_t)c * HW] * sc);
}

// ---- normalize img: (C,H,W) fp32 -> Q[h*64+w][c] bf16 ----
__global__ void norm_img_kernel(const float* __restrict__ img,
                                unsigned short* __restrict__ Q) {
  int h = blockIdx.x;
  int w = threadIdx.x;
  const float* base = img + h * WN + w;
  float ss = 0.f;
#pragma unroll 4
  for (int c = 0; c < CN; ++c) { float v = base[(size_t)c * HW]; ss += v * v; }
  float sc = 1.f / fmaxf(sqrtf(ss), 1e-12f);
  unsigned short* o = Q + ((size_t)(h * WN + w)) * KD;
#pragma unroll 4
  for (int c = 0; c < CN; ++c) o[c] = f2bf(base[(size_t)c * HW] * sc);
}

__global__ void init_out_kernel(float* __restrict__ out) {
  out[blockIdx.x * 256 + threadIdx.x] = -INFINITY;
}

// ---- GEMM-max: out[q] = max_r sum_k Q[q][k]*R[r][k] ----
__global__ __launch_bounds__(256, 2)
void simmax_kernel(const unsigned short* __restrict__ Q,
                   const unsigned short* __restrict__ R,
                   float* __restrict__ out) {
  __shared__ unsigned short As[BM * BK];   // [row][k], chunk-swizzled
  __shared__ unsigned short Bs[BN * BK];

  const int t    = threadIdx.x;
  const int lane = t & 63;
  const int wv   = t >> 6;          // 0..3
  const int wm   = wv >> 1;         // wave row (0..1)
  const int wn   = wv & 1;          // wave col (0..1)
  const int bm   = blockIdx.x;      // m-tile 0..31
  const int nch  = blockIdx.y;      // n-chunk 0..31

  const int srow   = lane >> 3;     // 0..7 (row within 8-row segment)
  const int schunk = lane & 7;      // 16B chunk within 128B row

  f32x4 run[4];
#pragma unroll
  for (int mi = 0; mi < 4; ++mi) {
    run[mi][0] = -1e30f; run[mi][1] = -1e30f; run[mi][2] = -1e30f; run[mi][3] = -1e30f;
  }

  for (int nt = 0; nt < NT_PER; ++nt) {
    const int rbase = (nch * NT_PER + nt) * BN;
    f32x4 acc[4][4];
#pragma unroll
    for (int mi = 0; mi < 4; ++mi)
#pragma unroll
      for (int ni = 0; ni < 4; ++ni) {
        acc[mi][ni][0] = 0.f; acc[mi][ni][1] = 0.f; acc[mi][ni][2] = 0.f; acc[mi][ni][3] = 0.f;
      }

#pragma unroll
    for (int kt = 0; kt < KD / BK; ++kt) {
      __syncthreads();   // previous tile's LDS reads done
      // stage A & B tiles: 16 segments x (8 rows x 64 bf16); wave handles segs i*4+wv
#pragma unroll
      for (int i = 0; i < 4; ++i) {
        int seg = i * 4 + wv;
        int row = seg * 8 + srow;
        int sc_ = schunk ^ (row & 7);            // pre-swizzled global source
        const unsigned short* srcA = Q + (size_t)(bm * BM + row) * KD + kt * BK + sc_ * 8;
        gload_lds16(srcA, &As[seg * 8 * BK]);
        const unsigned short* srcB = R + (size_t)(rbase + row) * KD + kt * BK + sc_ * 8;
        gload_lds16(srcB, &Bs[seg * 8 * BK]);
      }
      __syncthreads();   // staging complete (vmcnt(0) before barrier)

#pragma unroll
      for (int ks = 0; ks < 2; ++ks) {
        bf16x8 a[4], b[4];
#pragma unroll
        for (int mi = 0; mi < 4; ++mi) {
          int row = wm * 64 + mi * 16 + (lane & 15);
          int ch  = (ks * 4 + (lane >> 4)) ^ (row & 7);   // swizzled read
          a[mi] = *reinterpret_cast<const bf16x8*>(&As[row * BK + ch * 8]);
          int col = wn * 64 + mi * 16 + (lane & 15);
          int chb = (ks * 4 + (lane >> 4)) ^ (col & 7);
          b[mi] = *reinterpret_cast<const bf16x8*>(&Bs[col * BK + chb * 8]);
        }
#pragma unroll
        for (int mi = 0; mi < 4; ++mi)
#pragma unroll
          for (int ni = 0; ni < 4; ++ni)
            acc[mi][ni] = __builtin_amdgcn_mfma_f32_16x16x32_bf16(a[mi], b[ni], acc[mi][ni], 0, 0, 0);
      }
    }

    // fold this n-tile's 64 columns into per-lane running max (registers only)
#pragma unroll
    for (int mi = 0; mi < 4; ++mi)
#pragma unroll
      for (int e = 0; e < 4; ++e) {
        float v = fmaxf(fmaxf(acc[mi][0][e], acc[mi][1][e]),
                        fmaxf(acc[mi][2][e], acc[mi][3][e]));
        run[mi][e] = fmaxf(run[mi][e], v);
      }
  }

  // cross-lane reduce over the 16 column-lanes, then one atomic per row
#pragma unroll
  for (int mi = 0; mi < 4; ++mi)
#pragma unroll
    for (int e = 0; e < 4; ++e) {
      float v = run[mi][e];
      v = fmaxf(v, __shfl_xor(v, 1));
      v = fmaxf(v, __shfl_xor(v, 2));
      v = fmaxf(v, __shfl_xor(v, 4));
      v = fmaxf(v, __shfl_xor(v, 8));
      run[mi][e] = v;
    }

  if ((lane & 15) == 0) {
#pragma unroll
    for (int mi = 0; mi < 4; ++mi)
#pragma unroll
      for (int e = 0; e < 4; ++e) {
        int row = bm * BM + wm * 64 + mi * 16 + (lane >> 4) * 4 + e;
        atomicMaxFloat(&out[row], run[mi][e]);
      }
  }
}

extern "C" void kernel_launch(void* const* d_in, const int* in_sizes, int n_in,
                              void* d_out, int out_size, void* d_ws, size_t ws_size,
                              hipStream_t stream) {
  const float* refs = (const float*)d_in[0];
  const float* img  = (const float*)d_in[1];
  float* out = (float*)d_out;

  unsigned short* R = (unsigned short*)d_ws;                       // 131072*256 bf16 = 64MB
  unsigned short* Q = R + (size_t)NREF * KD;                       // 4096*256 bf16 = 2MB

  hipLaunchKernelGGL(norm_refs_kernel, dim3(NNW * HN), dim3(64), 0, stream, refs, R);
  hipLaunchKernelGGL(norm_img_kernel,  dim3(HN),       dim3(64), 0, stream, img, Q);
  hipLaunchKernelGGL(init_out_kernel,  dim3(HW / 256), dim3(256), 0, stream, out);
  hipLaunchKernelGGL(simmax_kernel,
                     dim3(HW / BM, NREF / (BN * NT_PER)), dim3(256), 0, stream,
                     Q, R, out);
}

// Round 2
// 285.230 us; speedup vs baseline: 1.4876x; 1.4876x over previous
//
#include <hip/hip_runtime.h>

#define CN 256
#define HN 64
#define WN 64
#define NNW 32
#define HW (HN*WN)            // 4096
#define NREF (NNW*HW)         // 131072
#define KD 256

#define BM 256
#define BN 256
#define NT2 32                // B-tiles per block
#define NKT (NT2*4)           // 128 K-step tiles per block
#define NITER (NKT/2)         // 64 iterations (2 tiles each)

using bf16x8 = __attribute__((ext_vector_type(8))) short;
using f32x4  = __attribute__((ext_vector_type(4))) float;

__device__ inline unsigned short f2bf(float x) {
  unsigned int u = __float_as_uint(x);
  return (unsigned short)((u + 0x7fffu + ((u >> 16) & 1u)) >> 16);
}

__device__ inline void atomicMaxFloat(float* addr, float val) {
  if (val >= 0.f) atomicMax(reinterpret_cast<int*>(addr), __float_as_int(val));
  else            atomicMin(reinterpret_cast<unsigned int*>(addr), __float_as_uint(val));
}

__device__ inline void gload_lds16(const void* g, void* l) {
  __builtin_amdgcn_global_load_lds(
      (const __attribute__((address_space(1))) void*)g,
      (__attribute__((address_space(3))) void*)l, 16, 0, 0);
}

// ---------------- normalize (refs blocks 0..2047, img blocks 2048..2111) ----
__global__ __launch_bounds__(256)
void norm_kernel(const float* __restrict__ refs, const float* __restrict__ img,
                 unsigned short* __restrict__ Rb, unsigned short* __restrict__ Qb,
                 float* __restrict__ out) {
  __shared__ float tile[CN][WN + 1];
  __shared__ float ssq[4][WN];
  __shared__ float scl[WN];
  const int bid = blockIdx.x;
  const int t = threadIdx.x;
  const float* src; unsigned short* dst; int nh;
  if (bid < NNW * HN) { src = refs; dst = Rb; nh = bid; }
  else {
    src = img; dst = Qb; nh = bid - NNW * HN;
    if (t < 64) out[(size_t)nh * 64 + t] = -INFINITY;   // init output
  }
  const float* base = src + (size_t)(nh >> 6) * (CN * (size_t)HW) + (size_t)(nh & 63) * WN;

  const int c16 = t >> 4, w4 = (t & 15) * 4;
#pragma unroll
  for (int j = 0; j < 16; ++j) {
    int c = j * 16 + c16;
    float4 v = *(const float4*)&base[(size_t)c * HW + w4];
    tile[c][w4 + 0] = v.x; tile[c][w4 + 1] = v.y;
    tile[c][w4 + 2] = v.z; tile[c][w4 + 3] = v.w;
  }
  __syncthreads();
  {
    int w = t & 63, vv = t >> 6;
    float s = 0.f;
#pragma unroll 8
    for (int cc = 0; cc < 64; ++cc) { float x = tile[vv * 64 + cc][w]; s += x * x; }
    ssq[vv][w] = s;
  }
  __syncthreads();
  if (t < 64)
    scl[t] = 1.f / fmaxf(sqrtf(ssq[0][t] + ssq[1][t] + ssq[2][t] + ssq[3][t]), 1e-12f);
  __syncthreads();
  const int w = t >> 2, cq = t & 3;
  unsigned short* orow = dst + ((size_t)nh * WN + w) * KD;
  const float sc = scl[w];
#pragma unroll
  for (int j = 0; j < 8; ++j) {
    int c0 = (j * 4 + cq) * 8;
    bf16x8 o;
#pragma unroll
    for (int k = 0; k < 8; ++k) o[k] = (short)f2bf(tile[c0 + k][w] * sc);
    *(bf16x8*)&orow[c0] = o;
  }
}

// ---------------- GEMM-max, 256x256 tile, 8-phase counted-vmcnt schedule ----
#define BARR() __builtin_amdgcn_s_barrier()
#define LGKM0() asm volatile("s_waitcnt lgkmcnt(0)" ::: "memory")
#define GATE(N) asm volatile("s_waitcnt vmcnt(" #N ")" ::: "memory")

#define DSR_A(SUB, MH) do { \
  _Pragma("unroll") \
  for (int mi = 0; mi < 4; ++mi) \
    a[mi] = *(const bf16x8*)&ldsA[(SUB)*8192 + aoff + ((MH)*64 + mi*16)*32]; \
} while (0)

#define DSR_B(SUB) do { \
  _Pragma("unroll") \
  for (int ni = 0; ni < 4; ++ni) \
    b[ni] = *(const bf16x8*)&ldsB[(SUB)*8192 + boff + (ni*16)*32]; \
} while (0)

#define MFMAS(MH) do { \
  __builtin_amdgcn_s_setprio(1); \
  _Pragma("unroll") \
  for (int mi = 0; mi < 4; ++mi) \
  _Pragma("unroll") \
  for (int ni = 0; ni < 4; ++ni) \
    acc[MH][mi][ni] = __builtin_amdgcn_mfma_f32_16x16x32_bf16(a[mi], b[ni], acc[MH][mi][ni], 0, 0, 0); \
  __builtin_amdgcn_s_setprio(0); \
} while (0)

#define STG_A(SUB, KOFF) do { \
  gload_lds16(qsrc0 + (KOFF),            &ldsA[(SUB)*8192 + wid*512]); \
  gload_lds16(qsrc0 + 128*KD + (KOFF),   &ldsA[(SUB)*8192 + (wid+8)*512]); \
} while (0)

#define STG_B(SUB, BOFF) do { \
  gload_lds16(rsrc0 + (BOFF),            &ldsB[(SUB)*8192 + wid*512]); \
  gload_lds16(rsrc0 + (BOFF) + 128*KD,   &ldsB[(SUB)*8192 + (wid+8)*512]); \
} while (0)

#define FOLD() do { \
  _Pragma("unroll") \
  for (int mh = 0; mh < 2; ++mh) \
  _Pragma("unroll") \
  for (int mi = 0; mi < 4; ++mi) \
  _Pragma("unroll") \
  for (int ee = 0; ee < 4; ++ee) { \
    float v0 = fmaxf(acc[mh][mi][0][ee], acc[mh][mi][1][ee]); \
    float v1 = fmaxf(acc[mh][mi][2][ee], acc[mh][mi][3][ee]); \
    run[mh][mi][ee] = fmaxf(run[mh][mi][ee], fmaxf(v0, v1)); \
    acc[mh][mi][0][ee] = 0.f; acc[mh][mi][1][ee] = 0.f; \
    acc[mh][mi][2][ee] = 0.f; acc[mh][mi][3][ee] = 0.f; \
  } \
} while (0)

__global__ __launch_bounds__(512, 2)
void simmax_kernel(const unsigned short* __restrict__ Q,
                   const unsigned short* __restrict__ R,
                   float* __restrict__ out) {
  // LDS: sub-buffer s = dbuf*2 + khalf, each 256 rows x 32 k bf16 = 16KB
  __shared__ unsigned short ldsA[4 * 8192];
  __shared__ unsigned short ldsB[4 * 8192];

  const int t = threadIdx.x;
  const int lane = t & 63;
  const int wid = t >> 6;        // 0..7
  const int wm = wid >> 2;       // 0..1
  const int wn = wid & 3;        // 0..3

  const int id = blockIdx.x;
  const int bm  = id >> 4;                         // 0..15
  const int nch = (id & 7) + 8 * ((id >> 3) & 1);  // XCD-colocated n-chunk

  // staging geometry: lane l covers row l>>2 (of 16-row group), phys chunk l&3,
  // pre-swizzled source chunk = (l&3) ^ ((l>>3)&3)
  const int stg_r = wid * 16 + (lane >> 2);
  const int stg_c = ((lane & 3) ^ ((lane >> 3) & 3)) * 8;
  const unsigned short* qsrc0 = Q + (size_t)(bm * BM + stg_r) * KD + stg_c;
  const unsigned short* rsrc0 = R + (size_t)((size_t)nch * NT2 * BN + stg_r) * KD + stg_c;

  // read geometry: phys = (lane>>4) ^ ((row>>1)&3); row base multiple of 16
  const int rA0 = wm * 128 + (lane & 15);
  const int rB0 = wn * 64 + (lane & 15);
  const int aoff = rA0 * 32 + (((lane >> 4) ^ ((rA0 >> 1) & 3)) * 8);
  const int boff = rB0 * 32 + (((lane >> 4) ^ ((rB0 >> 1) & 3)) * 8);

  f32x4 acc[2][4][4];
  f32x4 run[2][4];
#pragma unroll
  for (int mh = 0; mh < 2; ++mh)
#pragma unroll
    for (int mi = 0; mi < 4; ++mi) {
#pragma unroll
      for (int ee = 0; ee < 4; ++ee) run[mh][mi][ee] = -1e30f;
#pragma unroll
      for (int ni = 0; ni < 4; ++ni) {
        acc[mh][mi][ni][0] = 0.f; acc[mh][mi][ni][1] = 0.f;
        acc[mh][mi][ni][2] = 0.f; acc[mh][mi][ni][3] = 0.f;
      }
    }

  // prologue: tile0 (kh0,kh1) + tile1 (kh0); 12 loads/thread
  STG_A(0, 0);  STG_B(0, 0);
  STG_A(1, 32); STG_B(1, 32);
  STG_A(2, 64); STG_B(2, 64);
  GATE(8); BARR();

  for (int i = 0; i < NITER - 1; ++i) {
    const int e = 2 * i;
    const int k1  = ((e + 1) & 3) * 64 + 32;
    const int k2a = ((e + 2) & 3) * 64;
    const int k2b = k2a + 32;
    const int k3  = ((e + 3) & 3) * 64;
    const int b1  = ((e + 1) >> 2) * 65536 + k1;
    const int b2a = ((e + 2) >> 2) * 65536 + k2a;
    const int b2b = b2a + 32;
    const int b3  = ((e + 3) >> 2) * 65536 + k3;
    bf16x8 a[4], b[4];
    // p0: tile e kh0, mh0
    DSR_B(0); DSR_A(0, 0);
    STG_A(3, k1);
    BARR(); LGKM0(); MFMAS(0); BARR();
    // p1: tile e kh0, mh1
    DSR_A(0, 1);
    STG_B(3, b1);
    GATE(8); BARR(); LGKM0(); MFMAS(1); BARR();
    // p2: tile e kh1, mh0
    DSR_B(1); DSR_A(1, 0);
    STG_A(0, k2a);
    BARR(); LGKM0(); MFMAS(0); BARR();
    // p3: tile e kh1, mh1
    DSR_A(1, 1);
    STG_B(0, b2a);
    GATE(8); BARR(); LGKM0(); MFMAS(1); BARR();
    // p4: tile e+1 kh0, mh0
    DSR_B(2); DSR_A(2, 0);
    STG_A(1, k2b);
    BARR(); LGKM0(); MFMAS(0); BARR();
    // p5: tile e+1 kh0, mh1
    DSR_A(2, 1);
    STG_B(1, b2b);
    GATE(8); BARR(); LGKM0(); MFMAS(1); BARR();
    // p6: tile e+1 kh1, mh0
    DSR_B(3); DSR_A(3, 0);
    STG_A(2, k3);
    BARR(); LGKM0(); MFMAS(0); BARR();
    // p7: tile e+1 kh1, mh1
    DSR_A(3, 1);
    STG_B(2, b3);
    GATE(8); BARR(); LGKM0(); MFMAS(1); BARR();
    if (i & 1) FOLD();
  }

  // epilogue iteration (tiles 126,127): only tile127-kh1 still to stage
  {
    const int e = 2 * (NITER - 1);
    const int k1 = ((e + 1) & 3) * 64 + 32;
    const int b1 = ((e + 1) >> 2) * 65536 + k1;
    bf16x8 a[4], b[4];
    DSR_B(0); DSR_A(0, 0);
    STG_A(3, k1);
    BARR(); LGKM0(); MFMAS(0); BARR();
    DSR_A(0, 1);
    STG_B(3, b1);
    GATE(8); BARR(); LGKM0(); MFMAS(1); BARR();
    DSR_B(1); DSR_A(1, 0);
    BARR(); LGKM0(); MFMAS(0); BARR();
    DSR_A(1, 1);
    GATE(4); BARR(); LGKM0(); MFMAS(1); BARR();
    DSR_B(2); DSR_A(2, 0);
    BARR(); LGKM0(); MFMAS(0); BARR();
    DSR_A(2, 1);
    GATE(0); BARR(); LGKM0(); MFMAS(1); BARR();
    DSR_B(3); DSR_A(3, 0);
    BARR(); LGKM0(); MFMAS(0); BARR();
    DSR_A(3, 1);
    LGKM0(); MFMAS(1);
    FOLD();
  }

  // reduce over the 16 column-lanes, one atomic per output row
#pragma unroll
  for (int mh = 0; mh < 2; ++mh)
#pragma unroll
  for (int mi = 0; mi < 4; ++mi)
#pragma unroll
  for (int ee = 0; ee < 4; ++ee) {
    float v = run[mh][mi][ee];
    v = fmaxf(v, __shfl_xor(v, 1));
    v = fmaxf(v, __shfl_xor(v, 2));
    v = fmaxf(v, __shfl_xor(v, 4));
    v = fmaxf(v, __shfl_xor(v, 8));
    if ((lane & 15) == 0)
      atomicMaxFloat(&out[bm * BM + wm * 128 + mh * 64 + mi * 16 + (lane >> 4) * 4 + ee], v);
  }
}

extern "C" void kernel_launch(void* const* d_in, const int* in_sizes, int n_in,
                              void* d_out, int out_size, void* d_ws, size_t ws_size,
                              hipStream_t stream) {
  const float* refs = (const float*)d_in[0];
  const float* img  = (const float*)d_in[1];
  float* out = (float*)d_out;

  unsigned short* Rb = (unsigned short*)d_ws;                 // 131072*256 bf16 = 64MB
  unsigned short* Qb = Rb + (size_t)NREF * KD;                // 4096*256 bf16 = 2MB

  hipLaunchKernelGGL(norm_kernel, dim3(NNW * HN + HN), dim3(256), 0, stream,
                     refs, img, Rb, Qb, out);
  hipLaunchKernelGGL(simmax_kernel, dim3(256), dim3(512), 0, stream, Qb, Rb, out);
}

// Round 3
// 280.011 us; speedup vs baseline: 1.5154x; 1.0186x over previous
//
#include <hip/hip_runtime.h>

#define CN 256
#define HN 64
#define WN 64
#define NNW 32
#define HW (HN*WN)            // 4096
#define NREF (NNW*HW)         // 131072
#define KD 256

#define BM 256
#define BN 256
#define NT2 32                // B-tiles per block (each 256 refs x K=256)

using bf16x8 = __attribute__((ext_vector_type(8))) short;
using f32x4  = __attribute__((ext_vector_type(4))) float;

__device__ inline unsigned short f2bf(float x) {
  unsigned int u = __float_as_uint(x);
  return (unsigned short)((u + 0x7fffu + ((u >> 16) & 1u)) >> 16);
}

__device__ inline void atomicMaxFloat(float* addr, float val) {
  if (val >= 0.f) atomicMax(reinterpret_cast<int*>(addr), __float_as_int(val));
  else            atomicMin(reinterpret_cast<unsigned int*>(addr), __float_as_uint(val));
}

__device__ inline void gload_lds16(const void* g, void* l) {
  __builtin_amdgcn_global_load_lds(
      (const __attribute__((address_space(1))) void*)g,
      (__attribute__((address_space(3))) void*)l, 16, 0, 0);
}

// ---------------- normalize (refs blocks 0..2047, img blocks 2048..2111) ----
__global__ __launch_bounds__(256)
void norm_kernel(const float* __restrict__ refs, const float* __restrict__ img,
                 unsigned short* __restrict__ Rb, unsigned short* __restrict__ Qb,
                 float* __restrict__ out) {
  __shared__ float tile[CN][WN + 1];
  __shared__ float ssq[4][WN];
  __shared__ float scl[WN];
  const int bid = blockIdx.x;
  const int t = threadIdx.x;
  const float* src; unsigned short* dst; int nh;
  if (bid < NNW * HN) { src = refs; dst = Rb; nh = bid; }
  else {
    src = img; dst = Qb; nh = bid - NNW * HN;
    if (t < 64) out[(size_t)nh * 64 + t] = -INFINITY;   // init output
  }
  const float* base = src + (size_t)(nh >> 6) * (CN * (size_t)HW) + (size_t)(nh & 63) * WN;

  const int c16 = t >> 4, w4 = (t & 15) * 4;
#pragma unroll
  for (int j = 0; j < 16; ++j) {
    int c = j * 16 + c16;
    float4 v = *(const float4*)&base[(size_t)c * HW + w4];
    tile[c][w4 + 0] = v.x; tile[c][w4 + 1] = v.y;
    tile[c][w4 + 2] = v.z; tile[c][w4 + 3] = v.w;
  }
  __syncthreads();
  {
    int w = t & 63, vv = t >> 6;
    float s = 0.f;
#pragma unroll 8
    for (int cc = 0; cc < 64; ++cc) { float x = tile[vv * 64 + cc][w]; s += x * x; }
    ssq[vv][w] = s;
  }
  __syncthreads();
  if (t < 64)
    scl[t] = 1.f / fmaxf(sqrtf(ssq[0][t] + ssq[1][t] + ssq[2][t] + ssq[3][t]), 1e-12f);
  __syncthreads();
  const int w = t >> 2, cq = t & 3;
  unsigned short* orow = dst + ((size_t)nh * WN + w) * KD;
  const float sc = scl[w];
#pragma unroll
  for (int j = 0; j < 8; ++j) {
    int c0 = (j * 4 + cq) * 8;
    bf16x8 o;
#pragma unroll
    for (int k = 0; k < 8; ++k) o[k] = (short)f2bf(tile[c0 + k][w] * sc);
    *(bf16x8*)&orow[c0] = o;
  }
}

// ---------------- GEMM-max, 256x256 tile, merged-phase counted-vmcnt --------
#define BARR() __builtin_amdgcn_s_barrier()
#define LGKM0() asm volatile("s_waitcnt lgkmcnt(0)" ::: "memory")
#define GATE(N) asm volatile("s_waitcnt vmcnt(" #N ")" ::: "memory")

// read all 8 A-fragments (both mh) for one K-half sub-buffer
#define DSR_A2(SUB) do { \
  _Pragma("unroll") \
  for (int mi = 0; mi < 4; ++mi) { \
    a[mi]     = *(const bf16x8*)&ldsA[(SUB)*8192 + aoff + (mi*16)*32]; \
    a[4 + mi] = *(const bf16x8*)&ldsA[(SUB)*8192 + aoff + ((64 + mi*16))*32]; \
  } \
} while (0)

#define DSR_B(SUB) do { \
  _Pragma("unroll") \
  for (int ni = 0; ni < 4; ++ni) \
    b[ni] = *(const bf16x8*)&ldsB[(SUB)*8192 + boff + (ni*16)*32]; \
} while (0)

#define MFMAS2() do { \
  __builtin_amdgcn_s_setprio(1); \
  _Pragma("unroll") \
  for (int mh = 0; mh < 2; ++mh) \
  _Pragma("unroll") \
  for (int mi = 0; mi < 4; ++mi) \
  _Pragma("unroll") \
  for (int ni = 0; ni < 4; ++ni) \
    acc[mh][mi][ni] = __builtin_amdgcn_mfma_f32_16x16x32_bf16(a[mh*4+mi], b[ni], acc[mh][mi][ni], 0, 0, 0); \
  __builtin_amdgcn_s_setprio(0); \
} while (0)

// first K-half of a B-tile: C = 0 (no accumulator zeroing needed)
#define MFMAS2Z() do { \
  __builtin_amdgcn_s_setprio(1); \
  _Pragma("unroll") \
  for (int mh = 0; mh < 2; ++mh) \
  _Pragma("unroll") \
  for (int mi = 0; mi < 4; ++mi) \
  _Pragma("unroll") \
  for (int ni = 0; ni < 4; ++ni) \
    acc[mh][mi][ni] = __builtin_amdgcn_mfma_f32_16x16x32_bf16(a[mh*4+mi], b[ni], ZZ, 0, 0, 0); \
  __builtin_amdgcn_s_setprio(0); \
} while (0)

#define STG_A2(SUB, QOFF) do { \
  gload_lds16(qsrc0 + (QOFF),            &ldsA[(SUB)*8192 + wid*512]); \
  gload_lds16(qsrc0 + 128*KD + (QOFF),   &ldsA[(SUB)*8192 + (wid+8)*512]); \
} while (0)

#define STG_B2(SUB, PTR, BOFF) do { \
  gload_lds16((PTR) + (BOFF),            &ldsB[(SUB)*8192 + wid*512]); \
  gload_lds16((PTR) + (BOFF) + 128*KD,   &ldsB[(SUB)*8192 + (wid+8)*512]); \
} while (0)

#define FOLD2() do { \
  _Pragma("unroll") \
  for (int mh = 0; mh < 2; ++mh) \
  _Pragma("unroll") \
  for (int mi = 0; mi < 4; ++mi) \
  _Pragma("unroll") \
  for (int ee = 0; ee < 4; ++ee) { \
    float v0 = fmaxf(acc[mh][mi][0][ee], acc[mh][mi][1][ee]); \
    float v1 = fmaxf(acc[mh][mi][2][ee], acc[mh][mi][3][ee]); \
    run[mh][mi][ee] = fmaxf(run[mh][mi][ee], fmaxf(v0, v1)); \
  } \
} while (0)

__global__ __launch_bounds__(512, 2)
void simmax_kernel(const unsigned short* __restrict__ Q,
                   const unsigned short* __restrict__ R,
                   float* __restrict__ out) {
  // LDS: sub-buffer s = K-tile&3 alternating K-halves, each 256 rows x 32 k = 16KB
  __shared__ unsigned short ldsA[4 * 8192];
  __shared__ unsigned short ldsB[4 * 8192];

  const int t = threadIdx.x;
  const int lane = t & 63;
  const int wid = t >> 6;        // 0..7
  const int wm = wid >> 2;       // 0..1
  const int wn = wid & 3;        // 0..3

  const int id = blockIdx.x;
  const int bm  = id >> 4;       // 0..15
  const int nch = id & 15;       // same-nch blocks land on one XCD (id%8 fixed)

  // staging: lane covers row lane>>2 of 16-row group, phys chunk lane&3,
  // pre-swizzled source chunk = (lane&3) ^ ((lane>>3)&3)
  const int stg_r = wid * 16 + (lane >> 2);
  const int stg_c = ((lane & 3) ^ ((lane >> 3) & 3)) * 8;
  const unsigned short* qsrc0 = Q + (size_t)(bm * BM + stg_r) * KD + stg_c;
  const unsigned short* rsrc0 = R + (size_t)((size_t)nch * NT2 * BN + stg_r) * KD + stg_c;

  // read: phys chunk = (lane>>4) ^ ((row>>1)&3)
  const int rA0 = wm * 128 + (lane & 15);
  const int rB0 = wn * 64 + (lane & 15);
  const int aoff = rA0 * 32 + (((lane >> 4) ^ ((rA0 >> 1) & 3)) * 8);
  const int boff = rB0 * 32 + (((lane >> 4) ^ ((rB0 >> 1) & 3)) * 8);

  const f32x4 ZZ = {0.f, 0.f, 0.f, 0.f};
  f32x4 acc[2][4][4];
  f32x4 run[2][4];
#pragma unroll
  for (int mh = 0; mh < 2; ++mh)
#pragma unroll
    for (int mi = 0; mi < 4; ++mi)
#pragma unroll
      for (int ee = 0; ee < 4; ++ee) run[mh][mi][ee] = -1e30f;

  // prologue: sub0 (k=0), sub1 (k=32), sub2 (k=64)
  STG_A2(0, 0);  STG_B2(0, rsrc0, 0);
  STG_A2(1, 32); STG_B2(1, rsrc0, 32);
  STG_A2(2, 64); STG_B2(2, rsrc0, 64);
  GATE(8); BARR();

  const unsigned short* rs = rsrc0;
  for (int bt = 0; bt < NT2 - 1; ++bt) {
    bf16x8 a[8], b[4];
    // m0: sub0 (K-tile0 kh0), stage sub3 <- k=96          [C = 0]
    DSR_B(0); DSR_A2(0);
    STG_A2(3, 96); STG_B2(3, rs, 96);
    GATE(8); BARR(); LGKM0(); MFMAS2Z(); BARR();
    // m1: sub1 (k=32), stage sub0 <- k=128
    DSR_B(1); DSR_A2(1);
    STG_A2(0, 128); STG_B2(0, rs, 128);
    GATE(8); BARR(); LGKM0(); MFMAS2(); BARR();
    // m2: sub2 (k=64), stage sub1 <- k=160
    DSR_B(2); DSR_A2(2);
    STG_A2(1, 160); STG_B2(1, rs, 160);
    GATE(8); BARR(); LGKM0(); MFMAS2(); BARR();
    // m3: sub3 (k=96), stage sub2 <- k=192
    DSR_B(3); DSR_A2(3);
    STG_A2(2, 192); STG_B2(2, rs, 192);
    GATE(8); BARR(); LGKM0(); MFMAS2(); BARR();
    // m4: sub0 (k=128), stage sub3 <- k=224
    DSR_B(0); DSR_A2(0);
    STG_A2(3, 224); STG_B2(3, rs, 224);
    GATE(8); BARR(); LGKM0(); MFMAS2(); BARR();
    // m5: sub1 (k=160), stage sub0 <- next tile k=0
    DSR_B(1); DSR_A2(1);
    STG_A2(0, 0); STG_B2(0, rs, 65536);
    GATE(8); BARR(); LGKM0(); MFMAS2(); BARR();
    // m6: sub2 (k=192), stage sub1 <- next k=32
    DSR_B(2); DSR_A2(2);
    STG_A2(1, 32); STG_B2(1, rs, 65536 + 32);
    GATE(8); BARR(); LGKM0(); MFMAS2(); BARR();
    // m7: sub3 (k=224), stage sub2 <- next k=64
    DSR_B(3); DSR_A2(3);
    STG_A2(2, 64); STG_B2(2, rs, 65536 + 64);
    GATE(8); BARR(); LGKM0(); MFMAS2(); BARR();
    FOLD2();
    rs += 65536;
  }

  // epilogue B-tile (bt = NT2-1): no next-tile stages
  {
    bf16x8 a[8], b[4];
    DSR_B(0); DSR_A2(0);
    STG_A2(3, 96); STG_B2(3, rs, 96);
    GATE(8); BARR(); LGKM0(); MFMAS2Z(); BARR();
    DSR_B(1); DSR_A2(1);
    STG_A2(0, 128); STG_B2(0, rs, 128);
    GATE(8); BARR(); LGKM0(); MFMAS2(); BARR();
    DSR_B(2); DSR_A2(2);
    STG_A2(1, 160); STG_B2(1, rs, 160);
    GATE(8); BARR(); LGKM0(); MFMAS2(); BARR();
    DSR_B(3); DSR_A2(3);
    STG_A2(2, 192); STG_B2(2, rs, 192);
    GATE(8); BARR(); LGKM0(); MFMAS2(); BARR();
    DSR_B(0); DSR_A2(0);
    STG_A2(3, 224); STG_B2(3, rs, 224);
    GATE(8); BARR(); LGKM0(); MFMAS2(); BARR();
    DSR_B(1); DSR_A2(1);                       // staged at m2 (3 phases back)
    GATE(8); BARR(); LGKM0(); MFMAS2(); BARR();
    DSR_B(2); DSR_A2(2);                       // staged at m3
    GATE(4); BARR(); LGKM0(); MFMAS2(); BARR();
    DSR_B(3); DSR_A2(3);                       // staged at m4
    GATE(0); LGKM0(); MFMAS2();
    FOLD2();
  }

  // reduce over the 16 column-lanes, one atomic per output row
#pragma unroll
  for (int mh = 0; mh < 2; ++mh)
#pragma unroll
  for (int mi = 0; mi < 4; ++mi)
#pragma unroll
  for (int ee = 0; ee < 4; ++ee) {
    float v = run[mh][mi][ee];
    v = fmaxf(v, __shfl_xor(v, 1));
    v = fmaxf(v, __shfl_xor(v, 2));
    v = fmaxf(v, __shfl_xor(v, 4));
    v = fmaxf(v, __shfl_xor(v, 8));
    if ((lane & 15) == 0)
      atomicMaxFloat(&out[bm * BM + wm * 128 + mh * 64 + mi * 16 + (lane >> 4) * 4 + ee], v);
  }
}

extern "C" void kernel_launch(void* const* d_in, const int* in_sizes, int n_in,
                              void* d_out, int out_size, void* d_ws, size_t ws_size,
                              hipStream_t stream) {
  const float* refs = (const float*)d_in[0];
  const float* img  = (const float*)d_in[1];
  float* out = (float*)d_out;

  unsigned short* Rb = (unsigned short*)d_ws;                 // 131072*256 bf16 = 64MB
  unsigned short* Qb = Rb + (size_t)NREF * KD;                // 4096*256 bf16 = 2MB

  hipLaunchKernelGGL(norm_kernel, dim3(NNW * HN + HN), dim3(256), 0, stream,
                     refs, img, Rb, Qb, out);
  hipLaunchKernelGGL(simmax_kernel, dim3(256), dim3(512), 0, stream, Qb, Rb, out);
}